// Round 2
// baseline (463.925 us; speedup 1.0000x reference)
//
#include <hip/hip_runtime.h>
#include <math.h>

// Problem constants (fixed by setup_inputs):
// B=16, T=8, NT=128, C=512, H=W=28, HW=784, c8=64
constexpr int NT  = 128;
constexpr int C   = 512;
constexpr int HW  = 784;      // 28*28 = 196 float4
constexpr int C8  = 64;
constexpr int TT  = 8;
constexpr int BB  = 16;
constexpr float EPS = 1e-5f;

typedef float v4f __attribute__((ext_vector_type(4)));

// K1: spatial mean. One wave per 4 consecutive (nt,c) rows (4 independent
// accumulators -> 4x memory-level parallelism per wave vs 1 row/wave).
// Block = 256 threads = 4 waves = 16 rows; grid = 65536/16 = 4096.
__global__ __launch_bounds__(256) void k_mean(const float* __restrict__ x,
                                              float* __restrict__ xv) {
    const int wave = threadIdx.x >> 6;
    const int lane = threadIdx.x & 63;
    const size_t wid = (size_t)blockIdx.x * 4 + wave;      // 0..16383
    const float4* p = (const float4*)(x + wid * (size_t)(4 * HW));
    float s0 = 0.f, s1 = 0.f, s2 = 0.f, s3 = 0.f;
    for (int j = lane; j < HW / 4; j += 64) {              // 196 float4 per row
        float4 a = p[j];
        float4 b = p[j + 196];
        float4 c = p[j + 392];
        float4 d = p[j + 588];
        s0 += (a.x + a.y) + (a.z + a.w);
        s1 += (b.x + b.y) + (b.z + b.w);
        s2 += (c.x + c.y) + (c.z + c.w);
        s3 += (d.x + d.y) + (d.z + d.w);
    }
    #pragma unroll
    for (int off = 32; off; off >>= 1) {
        s0 += __shfl_xor(s0, off);
        s1 += __shfl_xor(s1, off);
        s2 += __shfl_xor(s2, off);
        s3 += __shfl_xor(s3, off);
    }
    if (lane == 0) {
        const float inv = 1.0f / HW;
        ((float4*)xv)[wid] = make_float4(s0 * inv, s1 * inv, s2 * inv, s3 * inv);
    }
}

// K2: fused lr (conv1x1+BN+ReLU, both branches) + temporal scan + attention.
// One block per batch b (scan is per-batch sequential -> no cross-block dep).
// 16 blocks x 256 threads. All intermediates live in LDS; only sig (256 KB)
// goes to global.
__global__ __launch_bounds__(256) void k_mid(
        const float* __restrict__ xv,
        const float* __restrict__ w1,
        const float* __restrict__ g1, const float* __restrict__ b1,
        const float* __restrict__ m1, const float* __restrict__ v1,
        const float* __restrict__ w2,
        const float* __restrict__ g2, const float* __restrict__ b2,
        const float* __restrict__ m2, const float* __restrict__ v2,
        const float* __restrict__ gamma_w, const float* __restrict__ gamma_b,
        const float* __restrict__ Wa_w, const float* __restrict__ Wa_b,
        float* __restrict__ sig) {
    __shared__ float sx[TT * C];        // 16 KB: xv rows for this batch
    __shared__ float slr[TT][2 * C8];   //  4 KB: [t][0:64]=left, [64:128]=right
    __shared__ float sN[TT][C8];        //  2 KB: scan states
    const int b = blockIdx.x;

    for (int i = threadIdx.x; i < TT * C; i += 256)
        sx[i] = xv[b * TT * C + i];
    __syncthreads();

    // ---- lr: 8 timesteps x 128 outputs. Thread (u = tid&127) owns channel u
    // for timesteps t0, t0+2, t0+4, t0+6 (t0 = tid>>7): w[k] loaded once,
    // used 4x; 4 independent FMA chains; BN branch is wave-uniform.
    {
        const int u  = threadIdx.x & 127;
        const int t0 = threadIdx.x >> 7;            // 0 or 1
        const int j  = u & 63;
        const float* __restrict__ w =
            (u < C8) ? (w1 + (size_t)j * C) : (w2 + (size_t)j * C);
        const float* x0 = sx + (t0 + 0) * C;
        const float* x1 = sx + (t0 + 2) * C;
        const float* x2 = sx + (t0 + 4) * C;
        const float* x3 = sx + (t0 + 6) * C;
        float a0 = 0.f, a1 = 0.f, a2 = 0.f, a3 = 0.f;
        #pragma unroll 8
        for (int k = 0; k < C; ++k) {
            const float wk = w[k];
            a0 = fmaf(x0[k], wk, a0);
            a1 = fmaf(x1[k], wk, a1);
            a2 = fmaf(x2[k], wk, a2);
            a3 = fmaf(x3[k], wk, a3);
        }
        float mm, sc, bb;
        if (u < C8) { mm = m1[j]; sc = rsqrtf(v1[j] + EPS) * g1[j]; bb = b1[j]; }
        else        { mm = m2[j]; sc = rsqrtf(v2[j] + EPS) * g2[j]; bb = b2[j]; }
        slr[t0 + 0][u] = fmaxf(fmaf(a0 - mm, sc, bb), 0.f);
        slr[t0 + 2][u] = fmaxf(fmaf(a1 - mm, sc, bb), 0.f);
        slr[t0 + 4][u] = fmaxf(fmaf(a2 - mm, sc, bb), 0.f);
        slr[t0 + 6][u] = fmaxf(fmaf(a3 - mm, sc, bb), 0.f);
    }
    __syncthreads();

    // ---- scan (wave 0 only). diff[t] = left[t] - right[t+1], diff[7]=1,
    // state0 = ones; scalar gate per (b,t) via 64-lane reduce.
    if (threadIdx.x < 64) {
        const int j = threadIdx.x;
        const float gw0 = gamma_w[j];
        const float gw1 = gamma_w[C8 + j];
        const float gb  = gamma_b[0];
        float d[TT];
        #pragma unroll
        for (int t = 0; t < TT - 1; ++t) d[t] = slr[t][j] - slr[t + 1][C8 + j];
        d[TT - 1] = 1.0f;
        float state = 1.0f;
        #pragma unroll
        for (int t = 0; t < TT; ++t) {
            float part = d[t] * gw0 + state * gw1;
            #pragma unroll
            for (int off = 32; off; off >>= 1) part += __shfl_xor(part, off);
            const float g = 1.f / (1.f + expf(-(part + gb)));
            state = d[t] * g + state * (1.f - g);
            sN[t][j] = state;
        }
    }
    __syncthreads();

    // ---- att: sig[b,t,c] = sigmoid(dot(sN[t], Wa_w[c]) + Wa_b[c]).
    // Each thread: channels c0 and c0+256 for all 8 t (2 independent chains).
    {
        const int c0 = threadIdx.x;
        const int c1 = threadIdx.x + 256;
        const float* __restrict__ wA = Wa_w + (size_t)c0 * C8;
        const float* __restrict__ wB = Wa_w + (size_t)c1 * C8;
        const float baseA = Wa_b[c0];
        const float baseB = Wa_b[c1];
        for (int t = 0; t < TT; ++t) {
            const float* n = sN[t];
            float accA = baseA, accB = baseB;
            #pragma unroll 8
            for (int k = 0; k < C8; ++k) {
                const float nk = n[k];
                accA = fmaf(nk, wA[k], accA);
                accB = fmaf(nk, wB[k], accB);
            }
            sig[(b * TT + t) * C + c0] = 1.f / (1.f + expf(-accA));
            sig[(b * TT + t) * C + c1] = 1.f / (1.f + expf(-accB));
        }
    }
}

// K3: out[row,:] = x[row,:] * sig[row]. One wave per 4 rows (4 load streams).
// Plain cached stores: round-1's nontemporal stores regressed ~30 us
// (NT bypasses the L2/L3 write-combine path that the 6.6 TB/s fill uses).
__global__ __launch_bounds__(256) void k_scale(const float* __restrict__ x,
                                               const float* __restrict__ sig,
                                               float* __restrict__ out) {
    const int wave = threadIdx.x >> 6;
    const int lane = threadIdx.x & 63;
    const size_t wid = (size_t)blockIdx.x * 4 + wave;      // 0..16383
    const float4 sv = ((const float4*)sig)[wid];
    const v4f* px = (const v4f*)(x + wid * (size_t)(4 * HW));
    v4f*       po = (v4f*)(out + wid * (size_t)(4 * HW));
    for (int j = lane; j < HW / 4; j += 64) {
        v4f a = px[j];
        v4f b = px[j + 196];
        v4f c = px[j + 392];
        v4f d = px[j + 588];
        po[j]       = a * sv.x;
        po[j + 196] = b * sv.y;
        po[j + 392] = c * sv.z;
        po[j + 588] = d * sv.w;
    }
}

extern "C" void kernel_launch(void* const* d_in, const int* in_sizes, int n_in,
                              void* d_out, int out_size, void* d_ws, size_t ws_size,
                              hipStream_t stream) {
    const float* x       = (const float*)d_in[0];
    const float* w1      = (const float*)d_in[1];
    const float* bn1_g   = (const float*)d_in[2];
    const float* bn1_b   = (const float*)d_in[3];
    const float* bn1_m   = (const float*)d_in[4];
    const float* bn1_v   = (const float*)d_in[5];
    const float* w2      = (const float*)d_in[6];
    const float* bn2_g   = (const float*)d_in[7];
    const float* bn2_b   = (const float*)d_in[8];
    const float* bn2_m   = (const float*)d_in[9];
    const float* bn2_v   = (const float*)d_in[10];
    const float* Wa_w    = (const float*)d_in[11];
    const float* Wa_b    = (const float*)d_in[12];
    const float* gamma_w = (const float*)d_in[13];
    const float* gamma_b = (const float*)d_in[14];
    float* out = (float*)d_out;

    // workspace layout (floats): xv[65536] | sig[65536]
    float* ws  = (float*)d_ws;
    float* xv  = ws;
    float* sig = xv + NT * C;

    const int rows = NT * C;                       // 65536
    k_mean <<<rows / 16, 256, 0, stream>>>(x, xv); // 4096 blocks
    k_mid  <<<BB, 256, 0, stream>>>(xv, w1, bn1_g, bn1_b, bn1_m, bn1_v,
                                        w2, bn2_g, bn2_b, bn2_m, bn2_v,
                                        gamma_w, gamma_b, Wa_w, Wa_b, sig);
    k_scale<<<rows / 16, 256, 0, stream>>>(x, sig, out);
}

// Round 3
// 445.522 us; speedup vs baseline: 1.0413x; 1.0413x over previous
//
#include <hip/hip_runtime.h>
#include <math.h>

// Problem constants (fixed by setup_inputs):
// B=16, T=8, NT=128, C=512, H=W=28, HW=784, c8=64
constexpr int NT  = 128;
constexpr int C   = 512;
constexpr int HW  = 784;      // 28*28, = 196 float4
constexpr int C8  = 64;
constexpr int TT  = 8;
constexpr int BB  = 16;
constexpr float EPS = 1e-5f;

// K1: spatial mean. One wave (64 lanes) per (nt,c) row of 784 floats.
// Block = 256 threads = 4 waves = 4 rows; grid = 65536/4 = 16384.
// (round-0 verified form — do not restructure: 4-row/wave variant regressed)
__global__ void k_mean(const float* __restrict__ x, float* __restrict__ xv) {
    const int wave = threadIdx.x >> 6;
    const int lane = threadIdx.x & 63;
    const size_t row = (size_t)blockIdx.x * 4 + wave;   // 0..65535
    const float4* p = (const float4*)(x + row * HW);
    float s = 0.f;
    #pragma unroll
    for (int j = lane; j < HW / 4; j += 64) {           // 196 float4 per row
        float4 v = p[j];
        s += v.x + v.y + v.z + v.w;
    }
    #pragma unroll
    for (int off = 32; off; off >>= 1) s += __shfl_xor(s, off);
    if (lane == 0) xv[row] = s * (1.0f / HW);
}

// K2: left/right = relu(bn(xv @ w^T)). One block per bt (128 blocks), 256 threads.
// 128 outputs per block (64 left + 64 right), 2 threads per output (256-MAC halves).
// (round-0 verified form)
__global__ void k_lr(const float* __restrict__ xv,
                     const float* __restrict__ w1,
                     const float* __restrict__ g1, const float* __restrict__ b1,
                     const float* __restrict__ m1, const float* __restrict__ v1,
                     const float* __restrict__ w2,
                     const float* __restrict__ g2, const float* __restrict__ b2,
                     const float* __restrict__ m2, const float* __restrict__ v2,
                     float* __restrict__ lr) {
    __shared__ float sx[C];
    const int bt = blockIdx.x;
    for (int i = threadIdx.x; i < C; i += 256) sx[i] = xv[bt * C + i];
    __syncthreads();

    const int out  = threadIdx.x >> 1;   // 0..127
    const int half = threadIdx.x & 1;
    const int j    = out & 63;
    const float* w = (out < C8) ? (w1 + (size_t)j * C) : (w2 + (size_t)j * C);
    const int k0 = half * (C / 2);
    float acc = 0.f;
    #pragma unroll 8
    for (int k = 0; k < C / 2; ++k) acc = fmaf(sx[k0 + k], w[k0 + k], acc);
    acc += __shfl_xor(acc, 1);
    if (half == 0) {
        float y;
        if (out < C8) y = (acc - m1[j]) * rsqrtf(v1[j] + EPS) * g1[j] + b1[j];
        else          y = (acc - m2[j]) * rsqrtf(v2[j] + EPS) * g2[j] + b2[j];
        lr[bt * 2 * C8 + out] = fmaxf(y, 0.f);
    }
}

// K3: merged scan + attention. One block per batch (16 blocks x 256 threads).
// Wave 0 runs the sequential gate scan (states -> LDS); then all 256 threads
// compute sig[b,t,c] = sigmoid(dot(state[t], Wa_w[c]) + Wa_b[c]).
// vs round-0: one fewer launch, and Wa_w is read by 16 blocks instead of 128.
__global__ __launch_bounds__(256) void k_scan_att(
        const float* __restrict__ lr,
        const float* __restrict__ gamma_w,
        const float* __restrict__ gamma_b,
        const float* __restrict__ Wa_w,
        const float* __restrict__ Wa_b,
        float* __restrict__ sig) {
    __shared__ float sN[TT][C8];
    const int b = blockIdx.x;    // 0..15

    if (threadIdx.x < 64) {
        const int j = threadIdx.x;   // 0..63
        const float gw0 = gamma_w[j];
        const float gw1 = gamma_w[C8 + j];
        const float gb  = gamma_b[0];

        float d[TT];
        #pragma unroll
        for (int t = 0; t < TT - 1; ++t)
            d[t] = lr[(b * TT + t) * (2 * C8) + j]
                 - lr[(b * TT + t + 1) * (2 * C8) + C8 + j];
        d[TT - 1] = 1.0f;

        float state = 1.0f;
        #pragma unroll
        for (int t = 0; t < TT; ++t) {
            float part = d[t] * gw0 + state * gw1;
            #pragma unroll
            for (int off = 32; off; off >>= 1) part += __shfl_xor(part, off);
            const float g = 1.f / (1.f + expf(-(part + gb)));
            state = d[t] * g + state * (1.f - g);
            sN[t][j] = state;
        }
    }
    __syncthreads();

    // attention: 8 t x 512 c outputs for this batch; thread covers (t, c) pairs
    // c = threadIdx.x + {0,256}, all t. Weight row w[c] read once per c.
    {
        const int c0 = threadIdx.x;
        const int c1 = threadIdx.x + 256;
        const float* __restrict__ wA = Wa_w + (size_t)c0 * C8;
        const float* __restrict__ wB = Wa_w + (size_t)c1 * C8;
        const float baseA = Wa_b[c0];
        const float baseB = Wa_b[c1];
        for (int t = 0; t < TT; ++t) {
            const float* n = sN[t];
            float accA = baseA, accB = baseB;
            #pragma unroll 8
            for (int k = 0; k < C8; ++k) {
                const float nk = n[k];
                accA = fmaf(nk, wA[k], accA);
                accB = fmaf(nk, wB[k], accB);
            }
            sig[(b * TT + t) * C + c0] = 1.f / (1.f + expf(-accA));
            sig[(b * TT + t) * C + c1] = 1.f / (1.f + expf(-accB));
        }
    }
}

// K4: out[row, :] = x[row, :] * sig[row], row = bt*C + c. Wave per row, float4.
// (round-0 verified form — plain cached stores)
__global__ void k_scale(const float* __restrict__ x,
                        const float* __restrict__ sig,
                        float* __restrict__ out) {
    const int wave = threadIdx.x >> 6;
    const int lane = threadIdx.x & 63;
    const size_t row = (size_t)blockIdx.x * 4 + wave;
    const float s = sig[row];
    const float4* px = (const float4*)(x + row * HW);
    float4*       po = (float4*)(out + row * HW);
    #pragma unroll
    for (int j = lane; j < HW / 4; j += 64) {
        float4 v = px[j];
        v.x *= s; v.y *= s; v.z *= s; v.w *= s;
        po[j] = v;
    }
}

extern "C" void kernel_launch(void* const* d_in, const int* in_sizes, int n_in,
                              void* d_out, int out_size, void* d_ws, size_t ws_size,
                              hipStream_t stream) {
    const float* x     = (const float*)d_in[0];
    const float* w1    = (const float*)d_in[1];
    const float* bn1_g = (const float*)d_in[2];
    const float* bn1_b = (const float*)d_in[3];
    const float* bn1_m = (const float*)d_in[4];
    const float* bn1_v = (const float*)d_in[5];
    const float* w2    = (const float*)d_in[6];
    const float* bn2_g = (const float*)d_in[7];
    const float* bn2_b = (const float*)d_in[8];
    const float* bn2_m = (const float*)d_in[9];
    const float* bn2_v = (const float*)d_in[10];
    const float* Wa_w  = (const float*)d_in[11];
    const float* Wa_b  = (const float*)d_in[12];
    const float* gamma_w = (const float*)d_in[13];
    const float* gamma_b = (const float*)d_in[14];
    float* out = (float*)d_out;

    // workspace layout (floats): xv[65536] | lr[16384] | sig[65536]
    float* ws  = (float*)d_ws;
    float* xv  = ws;
    float* lr  = xv + NT * C;
    float* sig = lr + NT * 2 * C8;

    const int rows = NT * C;                 // 65536
    k_mean    <<<rows / 4, 256, 0, stream>>>(x, xv);
    k_lr      <<<NT, 256, 0, stream>>>(xv, w1, bn1_g, bn1_b, bn1_m, bn1_v,
                                           w2, bn2_g, bn2_b, bn2_m, bn2_v, lr);
    k_scan_att<<<BB, 256, 0, stream>>>(lr, gamma_w, gamma_b, Wa_w, Wa_b, sig);
    k_scale   <<<rows / 4, 256, 0, stream>>>(x, sig, out);
}